// Round 8
// baseline (441.066 us; speedup 1.0000x reference)
//
#include <hip/hip_runtime.h>
#include <hip/hip_bf16.h>

typedef __attribute__((ext_vector_type(8))) short short8;   // 8 x bf16 MFMA frag
typedef __attribute__((ext_vector_type(4))) float f32x4;
typedef __attribute__((ext_vector_type(4))) unsigned int uint4v;
typedef __attribute__((ext_vector_type(2))) unsigned int uint2v;

#define NB 16384
#define NH 1024
#define NE 64
#define ND 128

// ---------- bf16 helpers ----------
static __device__ __forceinline__ unsigned short f2b(float x) {
  unsigned int u = __builtin_bit_cast(unsigned int, x);
  unsigned int r = (u + 0x7fffu + ((u >> 16) & 1u)) >> 16;   // RNE, finite inputs
  return (unsigned short)r;
}
static __device__ __forceinline__ float b2f_lo(unsigned int u) {
  return __builtin_bit_cast(float, u << 16);
}
static __device__ __forceinline__ float b2f_hi(unsigned int u) {
  return __builtin_bit_cast(float, u & 0xffff0000u);
}

// ---------- k0: prep (transposes + bias sum + bf16 bias) ----------
__global__ __launch_bounds__(256, 1) void k0_prep(
    const float* __restrict__ Wh_w, const float* __restrict__ We_w,
    const float* __restrict__ We_b,
    unsigned short* __restrict__ WeT, unsigned short* __restrict__ WhT,
    float* __restrict__ bsum, unsigned short* __restrict__ We_bb)
{
  __shared__ float tile[32][33];
  const int bid = blockIdx.x, t = threadIdx.x;
  const int i = t >> 5, j = t & 31;
  if (bid < 1024) {
    const int e = bid >> 4, tr = (bid >> 2) & 3, tc = bid & 3;
    const float* src = We_w + (size_t)e * 16384;
#pragma unroll
    for (int k = 0; k < 4; ++k)
      tile[i + 8 * k][j] = src[(size_t)(tr * 32 + i + 8 * k) * 128 + tc * 32 + j];
    __syncthreads();
    unsigned short* dst = WeT + (size_t)e * 16384;
#pragma unroll
    for (int k = 0; k < 4; ++k) {
      int row = i + 8 * k;
      dst[(size_t)(tc * 32 + row) * 128 + tr * 32 + j] = f2b(tile[j][row]);
    }
  } else if (bid < 1152) {
    const int tb = bid - 1024, tr = tb >> 2, tc = tb & 3;
#pragma unroll
    for (int k = 0; k < 4; ++k)
      tile[i + 8 * k][j] = Wh_w[(size_t)(tr * 32 + i + 8 * k) * 128 + tc * 32 + j];
    __syncthreads();
#pragma unroll
    for (int k = 0; k < 4; ++k) {
      int row = i + 8 * k;
      WhT[(size_t)(tc * 32 + row) * 1024 + tr * 32 + j] = f2b(tile[j][row]);
    }
  } else if (bid == 1152) {
    if (t < 128) {
      float s = 0.f;
      for (int e = 0; e < 64; ++e) s += We_b[e * 128 + t];
      bsum[t] = s;
    }
  } else {
    for (int k = t; k < NE * ND; k += 256) We_bb[k] = f2b(We_b[k]);
  }
}

// ---------- k1: r = hidden @ Wh + Wh_b   -> r_bf16[B][128] ----------
__global__ __launch_bounds__(256, 2) void k1_rgemm(
    const float* __restrict__ hidden, const unsigned short* __restrict__ WhT,
    const float* __restrict__ Wh_b, unsigned short* __restrict__ r_g)
{
  const int t = threadIdx.x;
  const int w = t >> 6, l = t & 63, c = l & 15, g = l >> 4;
  const int bg = w & 1, dh = w >> 1;
  const int b = blockIdx.x * 32 + 16 * bg + c;
  const float* hrow = hidden + (size_t)b * NH;
  f32x4 acc[4];
#pragma unroll
  for (int mf = 0; mf < 4; ++mf) acc[mf] = (f32x4){0.f, 0.f, 0.f, 0.f};
#pragma unroll 2
  for (int ks = 0; ks < 32; ++ks) {
    const int k0 = 8 * g + 32 * ks;
    f32x4 h0 = *(const f32x4*)(hrow + k0);
    f32x4 h1 = *(const f32x4*)(hrow + k0 + 4);
    short8 bf;
    bf[0] = (short)f2b(h0[0]); bf[1] = (short)f2b(h0[1]);
    bf[2] = (short)f2b(h0[2]); bf[3] = (short)f2b(h0[3]);
    bf[4] = (short)f2b(h1[0]); bf[5] = (short)f2b(h1[1]);
    bf[6] = (short)f2b(h1[2]); bf[7] = (short)f2b(h1[3]);
#pragma unroll
    for (int mf = 0; mf < 4; ++mf) {
      short8 af = *(const short8*)(WhT + (size_t)(64 * dh + 16 * mf + c) * NH + k0);
      acc[mf] = __builtin_amdgcn_mfma_f32_16x16x32_bf16(af, bf, acc[mf], 0, 0, 0);
    }
  }
#pragma unroll
  for (int mf = 0; mf < 4; ++mf) {
    const int d0 = 64 * dh + 16 * mf + 4 * g;
    f32x4 bias = *(const f32x4*)(Wh_b + d0);
    f32x4 v = acc[mf] + bias;
    unsigned int lo = (unsigned)f2b(v[0]) | ((unsigned)f2b(v[1]) << 16);
    unsigned int hi = (unsigned)f2b(v[2]) | ((unsigned)f2b(v[3]) << 16);
    uint2v pk = {lo, hi};
    *(uint2v*)(r_g + (size_t)b * ND + d0) = pk;
  }
}

// ---------- k2: barrier-free fused kernel ----------
// 1024 blocks x 128 threads (2 waves). Block owns 16 b-rows; wave wv handles
// entities wv*32..wv*32+31 for those SAME rows; partial vt combined once at
// the end (the only __syncthreads in the kernel). Within the e-loop each wave
// is fully autonomous: softmax is in-register (+2 shfl), P redistribution for
// GEMM2 goes through a wave-PRIVATE swizzled LDS slice (lgkm-ordered).

// write one P slice (16 rows x 128 f32 = 8KB) to global, nt, 512B runs
static __device__ __forceinline__ void store_slice(
    const unsigned short* __restrict__ slice, float* __restrict__ outP,
    int brow0, int e, int l)
{
#pragma unroll
  for (int it = 0; it < 8; ++it) {
    const int f = it * 256 + l * 4;          // f32 idx in [0, 16*128)
    const int row = f >> 7, col = f & 127;   // col multiple of 4
    const int addr = row * 128 + ((((col >> 3) ^ row) & 15) << 3) + (col & 7);
    uint2v u = *(const uint2v*)(slice + addr);
    f32x4 v;
    v[0] = b2f_lo(u[0]); v[1] = b2f_hi(u[0]);
    v[2] = b2f_lo(u[1]); v[3] = b2f_hi(u[1]);
    __builtin_nontemporal_store(
        v, (f32x4*)(outP + ((size_t)(brow0 + row) * NE + e) * ND + col));
  }
}

__global__ __launch_bounds__(128, 2) void k2_main(
    const unsigned short* __restrict__ r_g, const unsigned short* __restrict__ WeT,
    const unsigned short* __restrict__ We_bb, const float* __restrict__ bsum,
    float* __restrict__ outP, float* __restrict__ outR)
{
  __shared__ unsigned short P_ring[2][2][16 * 128];   // [wave][slice] 16KB
  __shared__ float obuf[16 * 128];                    // 8KB combine buffer
  const int t = threadIdx.x;
  const int wv = t >> 6, l = t & 63, c = l & 15, g = l >> 4;
  // XCD-bijective remap (1024 = 8 x 128)
  const int lb = (blockIdx.x & 7) * 128 + (blockIdx.x >> 3);
  const int brow0 = lb * 16;
  const int ebase = wv * 32;
  const int phase = (blockIdx.x & 3) * 8;
  unsigned short* ring = &P_ring[wv][0][0];

  // r fragments for this block's 16 rows (held in registers all along)
  short8 rf[4];
#pragma unroll
  for (int ks = 0; ks < 4; ++ks)
    rf[ks] = *(const short8*)(r_g + (size_t)(brow0 + c) * ND + 8 * g + 32 * ks);

  f32x4 acc2[8];
#pragma unroll
  for (int n = 0; n < 8; ++n) acc2[n] = (f32x4){0.f, 0.f, 0.f, 0.f};

#pragma unroll 1
  for (int i = 0; i < 32; ++i) {
    const int e = ebase + ((i + phase) & 31);
    const unsigned short* we = WeT + (size_t)e * (ND * ND);
    // (a) issue ALL loads for this entity first (ks-major so GEMM1 starts
    // after the first 8 land); stores issued after -> no vmcnt wait below
    // ever requires a store to retire (in-order vm retirement).
    short8 f[8][4];
#pragma unroll
    for (int ks = 0; ks < 4; ++ks)
#pragma unroll
      for (int m = 0; m < 8; ++m)
        f[m][ks] = *(const short8*)(we + (size_t)(16 * m + c) * ND + 8 * g + 32 * ks);
    uint2v bb[8];
#pragma unroll
    for (int m = 0; m < 8; ++m)
      bb[m] = *(const uint2v*)(We_bb + (size_t)e * ND + 16 * m + 4 * g);
    // (b) write-behind: previous entity's P slice streams out under GEMM1
    if (i > 0) {
      const int ep = ebase + ((i - 1 + phase) & 31);
      store_slice(ring + ((i + 1) & 1) * 2048, outP, brow0, ep, l);
    }
    __builtin_amdgcn_sched_barrier(0);
    // (c) GEMM1: C[d][b] for all 128 d x 16 b of this wave
    f32x4 a1[8];
#pragma unroll
    for (int m = 0; m < 8; ++m) a1[m] = (f32x4){0.f, 0.f, 0.f, 0.f};
#pragma unroll
    for (int ks = 0; ks < 4; ++ks)
#pragma unroll
      for (int m = 0; m < 8; ++m)
        a1[m] = __builtin_amdgcn_mfma_f32_16x16x32_bf16(f[m][ks], rf[ks], a1[m], 0, 0, 0);
    // (d) bias + exp + wave-local softmax sum (lane has b=c, d=16m+4g+r)
    float s = 0.f;
#pragma unroll
    for (int m = 0; m < 8; ++m) {
      float b0 = b2f_lo(bb[m][0]), b1 = b2f_hi(bb[m][0]);
      float b2 = b2f_lo(bb[m][1]), b3 = b2f_hi(bb[m][1]);
      float p0 = __expf(a1[m][0] + b0); float p1 = __expf(a1[m][1] + b1);
      float p2 = __expf(a1[m][2] + b2); float p3 = __expf(a1[m][3] + b3);
      a1[m][0] = p0; a1[m][1] = p1; a1[m][2] = p2; a1[m][3] = p3;
      s += (p0 + p1) + (p2 + p3);
    }
    s += __shfl_xor(s, 16);
    s += __shfl_xor(s, 32);
    const float inv = 1.f / s;
    // (e) normalized P -> wave-private swizzled LDS slice (i&1)
    unsigned short* dst = ring + (i & 1) * 2048;
#pragma unroll
    for (int m = 0; m < 8; ++m) {
      f32x4 p = a1[m] * inv;
      unsigned int lo = (unsigned)f2b(p[0]) | ((unsigned)f2b(p[1]) << 16);
      unsigned int hi = (unsigned)f2b(p[2]) | ((unsigned)f2b(p[3]) << 16);
      uint2v pk = {lo, hi};
      const int chunk = (2 * m + (g >> 1)) ^ c;        // 16B-chunk swizzle
      *(uint2v*)(dst + c * 128 + (chunk << 3) + ((g & 1) << 2)) = pk;
    }
    // (f) GEMM2: vt[b][d'] += P x We^T  (A from LDS, B reuses f[][])
#pragma unroll
    for (int ks2 = 0; ks2 < 4; ++ks2) {
      short8 af = *(const short8*)(dst + c * 128 + (((g + 4 * ks2) ^ c) << 3));
#pragma unroll
      for (int n = 0; n < 8; ++n)
        acc2[n] = __builtin_amdgcn_mfma_f32_16x16x32_bf16(af, f[n][ks2], acc2[n], 0, 0, 0);
    }
  }
  // drain: last entity's slice (parity 1)
  store_slice(ring + 2048, outP, brow0, ebase + ((31 + phase) & 31), l);

  // ---- combine the two waves' vt partials; write result (only barrier)
  // acc2 lane layout: vt[b = 4g + r][d' = c + 16n]
  if (wv == 1) {
#pragma unroll
    for (int n = 0; n < 8; ++n)
#pragma unroll
      for (int r = 0; r < 4; ++r)
        obuf[(4 * g + r) * ND + c + 16 * n] = acc2[n][r];
  }
  __syncthreads();
  if (wv == 0) {
#pragma unroll
    for (int n = 0; n < 8; ++n) {
      const float bs = bsum[c + 16 * n];
#pragma unroll
      for (int r = 0; r < 4; ++r) {
        const int idx = (4 * g + r) * ND + c + 16 * n;
        obuf[idx] = acc2[n][r] + obuf[idx] + bs;      // in-place, lane-owned
      }
    }
#pragma unroll
    for (int it = 0; it < 8; ++it) {
      const int ff = it * 256 + l * 4;
      const int row = ff >> 7, col = ff & 127;
      f32x4 v = *(const f32x4*)(&obuf[row * ND + col]);
      __builtin_nontemporal_store(
          v, (f32x4*)(outR + (size_t)(brow0 + row) * ND + col));
    }
  }
}

extern "C" void kernel_launch(void* const* d_in, const int* in_sizes, int n_in,
                              void* d_out, int out_size, void* d_ws, size_t ws_size,
                              hipStream_t stream)
{
  (void)in_sizes; (void)n_in; (void)out_size; (void)ws_size;
  const float* hidden = (const float*)d_in[0];
  const float* Wh_w   = (const float*)d_in[1];
  const float* Wh_b   = (const float*)d_in[2];
  const float* We_w   = (const float*)d_in[3];
  const float* We_b   = (const float*)d_in[4];
  float* outP = (float*)d_out;
  float* outR = outP + (size_t)NB * NE * ND;

  char* ws = (char*)d_ws;
  unsigned short* WeT   = (unsigned short*)(ws);                      // 2MB
  unsigned short* WhT   = (unsigned short*)(ws + 2097152);            // 256KB
  unsigned short* r_g   = (unsigned short*)(ws + 2359296);            // 4MB
  float*          bsum  = (float*)(ws + 6553600);                     // 512B
  unsigned short* We_bb = (unsigned short*)(ws + 6554112);            // 16KB

  k0_prep<<<1154, 256, 0, stream>>>(Wh_w, We_w, We_b, WeT, WhT, bsum, We_bb);
  k1_rgemm<<<512, 256, 0, stream>>>(hidden, WhT, Wh_b, r_g);
  k2_main<<<1024, 128, 0, stream>>>(r_g, WeT, We_bb, bsum, outP, outR);
}

// Round 9
// 247.391 us; speedup vs baseline: 1.7829x; 1.7829x over previous
//
#include <hip/hip_runtime.h>
#include <hip/hip_bf16.h>

typedef __attribute__((ext_vector_type(8))) short short8;   // 8 x bf16 MFMA frag
typedef __attribute__((ext_vector_type(4))) float f32x4;
typedef __attribute__((ext_vector_type(4))) unsigned int uint4v;
typedef __attribute__((ext_vector_type(2))) unsigned int uint2v;

#define NB 16384
#define NH 1024
#define NE 64
#define ND 128
#define BR 32     // b-rows per k2 block

// ---------- bf16 helpers ----------
static __device__ __forceinline__ unsigned short f2b(float x) {
  unsigned int u = __builtin_bit_cast(unsigned int, x);
  unsigned int r = (u + 0x7fffu + ((u >> 16) & 1u)) >> 16;   // RNE, finite inputs
  return (unsigned short)r;
}
static __device__ __forceinline__ float b2f_lo(unsigned int u) {
  return __builtin_bit_cast(float, u << 16);
}
static __device__ __forceinline__ float b2f_hi(unsigned int u) {
  return __builtin_bit_cast(float, u & 0xffff0000u);
}

// raw barrier: drain LDS only (global stores keep flowing across barriers)
static __device__ __forceinline__ void bar_sync() {
  __builtin_amdgcn_sched_barrier(0);
  asm volatile("s_waitcnt lgkmcnt(0)" ::: "memory");
  __builtin_amdgcn_sched_barrier(0);
  __builtin_amdgcn_s_barrier();
  __builtin_amdgcn_sched_barrier(0);
}

// XOR-swizzled index into a [rows][128] bf16 tile (16B chunks, key row&15)
static __device__ __forceinline__ int swz(int row, int col) {
  return (row << 7) + ((((col >> 3) ^ (row & 15)) << 3) | (col & 7));
}

// ---------- k0: prep (transposes + bias sum) ----------
__global__ __launch_bounds__(256, 1) void k0_prep(
    const float* __restrict__ Wh_w, const float* __restrict__ We_w,
    const float* __restrict__ We_b,
    unsigned short* __restrict__ WeT, unsigned short* __restrict__ WhT,
    float* __restrict__ bsum)
{
  __shared__ float tile[32][33];
  const int bid = blockIdx.x, t = threadIdx.x;
  const int i = t >> 5, j = t & 31;
  if (bid < 1024) {
    const int e = bid >> 4, tr = (bid >> 2) & 3, tc = bid & 3;
    const float* src = We_w + (size_t)e * 16384;
#pragma unroll
    for (int k = 0; k < 4; ++k)
      tile[i + 8 * k][j] = src[(size_t)(tr * 32 + i + 8 * k) * 128 + tc * 32 + j];
    __syncthreads();
    unsigned short* dst = WeT + (size_t)e * 16384;
#pragma unroll
    for (int k = 0; k < 4; ++k) {
      int row = i + 8 * k;
      dst[(size_t)(tc * 32 + row) * 128 + tr * 32 + j] = f2b(tile[j][row]);
    }
  } else if (bid < 1152) {
    const int tb = bid - 1024, tr = tb >> 2, tc = tb & 3;
#pragma unroll
    for (int k = 0; k < 4; ++k)
      tile[i + 8 * k][j] = Wh_w[(size_t)(tr * 32 + i + 8 * k) * 128 + tc * 32 + j];
    __syncthreads();
#pragma unroll
    for (int k = 0; k < 4; ++k) {
      int row = i + 8 * k;
      WhT[(size_t)(tc * 32 + row) * 1024 + tr * 32 + j] = f2b(tile[j][row]);
    }
  } else {
    if (t < 128) {
      float s = 0.f;
      for (int e = 0; e < 64; ++e) s += We_b[e * 128 + t];
      bsum[t] = s;
    }
  }
}

// ---------- k2: fused kernel (512 blocks x 32 rows, 4 waves, 2 blocks/CU) ----
struct SmemK2 {
  union {
    unsigned short Pst[2][BR * 128];    // 16KB P ring (2 slices, unnormalized)
    float obuf[BR * 128];               // 16KB, epilogue reuse
  };
  unsigned short r_lds[BR * 128];       // 8KB, swizzled
  float sms[2][4][BR];                  // per-parity cross-wave sum partials
  float invr[2][BR];                    // per-parity 1/sum for the store path
};

// prefetch next entity's We fragments + bias (both L2-resident)
static __device__ __forceinline__ void load_we_frags(
    short8 (&f)[2][4], f32x4 (&bias)[2],
    const unsigned short* __restrict__ WeT, const float* __restrict__ We_b,
    int e, int w, int c, int g)
{
  const unsigned short* base = WeT + (size_t)e * (ND * ND);
#pragma unroll
  for (int mf = 0; mf < 2; ++mf) {
    const unsigned short* rowp = base + (size_t)(16 * (2 * w + mf) + c) * ND + 8 * g;
#pragma unroll
    for (int ks = 0; ks < 4; ++ks)
      f[mf][ks] = *(const short8*)(rowp + 32 * ks);
    bias[mf] = *(const f32x4*)(We_b + e * ND + 32 * w + 16 * mf + 4 * g);
  }
}

// write-behind: stream prev entity's P slice, normalizing with invr[sp].
// Per instruction: 64 lanes x contiguous 16B = two aligned 512B runs, nt.
static __device__ __forceinline__ void store_p_slice(
    const SmemK2& sm, float* __restrict__ outP,
    int brow0, int e_prev, int sp, int t)
{
#pragma unroll
  for (int it = 0; it < 4; ++it) {
    const int flat = it * 1024 + t * 4;      // f32 idx in [0, BR*ND)
    const int row = flat >> 7;
    const int col = flat & 127;
    const float inv = sm.invr[sp][row];
    uint2v u = *(const uint2v*)(&sm.Pst[sp][swz(row, col)]);
    f32x4 v;
    v[0] = b2f_lo(u[0]) * inv; v[1] = b2f_hi(u[0]) * inv;
    v[2] = b2f_lo(u[1]) * inv; v[3] = b2f_hi(u[1]) * inv;
    float* dst = outP + ((size_t)(brow0 + row) * NE + e_prev) * ND + col;
    __builtin_nontemporal_store(v, (f32x4*)dst);
  }
}

static __device__ __forceinline__ void entity_body(
    int i, int en, int ep, int brow0, int w, int c, int g, int t,
    short8 (&cur)[2][4], short8 (&nxt)[2][4],
    f32x4 (&bcur)[2], f32x4 (&bnxt)[2], f32x4 (&acc2)[2][2],
    const unsigned short* __restrict__ WeT, const float* __restrict__ We_b,
    float* __restrict__ outP, SmemK2& sm)
{
  const int si = i & 1, sp = si ^ 1;
  // 1. ALL loads for the next entity first; stores after -> no vmcnt wait
  //    below ever requires a store to retire (in-order vm retirement).
  load_we_frags(nxt, bnxt, WeT, We_b, en, w, c, g);
  __builtin_amdgcn_sched_barrier(0);
  // 2. write-behind: previous entity's slice streams out under GEMM1
  if (i > 0) store_p_slice(sm, outP, brow0, ep, sp, t);
  __builtin_amdgcn_sched_barrier(0);
  // 3. GEMM1: L^T[d][b], wave w owns d in [32w, 32w+32)
  f32x4 acc1[2][2];
#pragma unroll
  for (int mf = 0; mf < 2; ++mf)
#pragma unroll
    for (int nf = 0; nf < 2; ++nf) acc1[mf][nf] = (f32x4){0.f, 0.f, 0.f, 0.f};
#pragma unroll
  for (int ks = 0; ks < 4; ++ks) {
    short8 b1[2];
#pragma unroll
    for (int nf = 0; nf < 2; ++nf)
      b1[nf] = *(const short8*)(&sm.r_lds[swz(16 * nf + c, 8 * g + 32 * ks)]);
#pragma unroll
    for (int mf = 0; mf < 2; ++mf)
#pragma unroll
      for (int nf = 0; nf < 2; ++nf)
        acc1[mf][nf] = __builtin_amdgcn_mfma_f32_16x16x32_bf16(
            cur[mf][ks], b1[nf], acc1[mf][nf], 0, 0, 0);
  }
  // 4. bias + exp (UNNORMALIZED; |logits| small, no max-pass) + partial sums
#pragma unroll
  for (int mf = 0; mf < 2; ++mf)
#pragma unroll
    for (int nf = 0; nf < 2; ++nf) acc1[mf][nf] += bcur[mf];
  float s[2] = {0.f, 0.f};
#pragma unroll
  for (int nf = 0; nf < 2; ++nf) {
#pragma unroll
    for (int mf = 0; mf < 2; ++mf)
#pragma unroll
      for (int r = 0; r < 4; ++r) {
        float p = __expf(acc1[mf][nf][r]);
        acc1[mf][nf][r] = p;
        s[nf] += p;
      }
    s[nf] += __shfl_xor(s[nf], 16);
    s[nf] += __shfl_xor(s[nf], 32);
  }
  if (g == 0) {
    sm.sms[si][w][c] = s[0];
    sm.sms[si][w][16 + c] = s[1];
  }
  // 5. pack unnormalized expP bf16 -> Pst[si] (swizzled)
#pragma unroll
  for (int mf = 0; mf < 2; ++mf)
#pragma unroll
    for (int nf = 0; nf < 2; ++nf) {
      f32x4 p = acc1[mf][nf];
      unsigned int lo = (unsigned)f2b(p[0]) | ((unsigned)f2b(p[1]) << 16);
      unsigned int hi = (unsigned)f2b(p[2]) | ((unsigned)f2b(p[3]) << 16);
      uint2v pk = {lo, hi};
      *(uint2v*)(&sm.Pst[si][swz(16 * nf + c, 32 * w + 16 * mf + 4 * g)]) = pk;
    }
  bar_sync();                                   // the ONLY barrier per entity
  // 6. totals -> inv (approx rcp; error 2^-22 << bf16's 2^-9)
  f32x4 inv4[2];
#pragma unroll
  for (int mf2 = 0; mf2 < 2; ++mf2) {
    const int b0 = 16 * mf2 + 4 * g;
    f32x4 sv = *(const f32x4*)(&sm.sms[si][0][b0]);
    sv += *(const f32x4*)(&sm.sms[si][1][b0]);
    sv += *(const f32x4*)(&sm.sms[si][2][b0]);
    sv += *(const f32x4*)(&sm.sms[si][3][b0]);
#pragma unroll
    for (int r = 0; r < 4; ++r) inv4[mf2][r] = __builtin_amdgcn_rcpf(sv[r]);
  }
  if (g == 0) {
#pragma unroll
    for (int nf = 0; nf < 2; ++nf) {
      const int b = 16 * nf + c;
      float st = sm.sms[si][0][b] + sm.sms[si][1][b] +
                 sm.sms[si][2][b] + sm.sms[si][3][b];
      sm.invr[si][b] = __builtin_amdgcn_rcpf(st);
    }
  }
  // 7. GEMM2 on unnormalized P into fresh acc, then deferred per-row scale
  f32x4 eacc[2][2];
#pragma unroll
  for (int mf2 = 0; mf2 < 2; ++mf2)
#pragma unroll
    for (int n = 0; n < 2; ++n) eacc[mf2][n] = (f32x4){0.f, 0.f, 0.f, 0.f};
#pragma unroll
  for (int ks2 = 0; ks2 < 4; ++ks2) {
    short8 a2[2];
#pragma unroll
    for (int mf2 = 0; mf2 < 2; ++mf2)
      a2[mf2] = *(const short8*)(&sm.Pst[si][swz(16 * mf2 + c, 8 * g + 32 * ks2)]);
#pragma unroll
    for (int mf2 = 0; mf2 < 2; ++mf2)
#pragma unroll
      for (int n = 0; n < 2; ++n)
        eacc[mf2][n] = __builtin_amdgcn_mfma_f32_16x16x32_bf16(
            a2[mf2], cur[n][ks2], eacc[mf2][n], 0, 0, 0);
  }
#pragma unroll
  for (int mf2 = 0; mf2 < 2; ++mf2)
#pragma unroll
    for (int n = 0; n < 2; ++n)
      acc2[mf2][n] += eacc[mf2][n] * inv4[mf2];
}

__global__ __launch_bounds__(256, 2) void k2_main(
    const float* __restrict__ hidden, const unsigned short* __restrict__ WhT,
    const float* __restrict__ Wh_b, const unsigned short* __restrict__ WeT,
    const float* __restrict__ We_b, const float* __restrict__ bsum,
    float* __restrict__ outP, float* __restrict__ outR)
{
  __shared__ SmemK2 sm;
  const int t = threadIdx.x;
  const int w = t >> 6, l = t & 63, c = l & 15, g = l >> 4;
  // XCD-bijective remap: XCD x owns logical blocks [x*64, x*64+64)
  const int lb = (blockIdx.x & 7) * 64 + (blockIdx.x >> 3);
  const int brow0 = lb * BR;
  // phase-stagger: co-resident blocks get different e0
  const int e0 = (((lb >> 6) + lb) & 7) << 3;

  // first entity's We frags start loading immediately (L2)
  short8 wa[2][4], wb[2][4];
  f32x4 ba[2], bb[2];
  load_we_frags(wa, ba, WeT, We_b, e0, w, c, g);

  // ---- fused k1: r tile for this block's 32 rows -> r_lds (swizzled)
  {
    f32x4 pacc[2][2];
#pragma unroll
    for (int mf = 0; mf < 2; ++mf)
#pragma unroll
      for (int nf = 0; nf < 2; ++nf) pacc[mf][nf] = (f32x4){0.f, 0.f, 0.f, 0.f};
    const float* h0p = hidden + (size_t)(brow0 + c) * NH;
    const float* h1p = hidden + (size_t)(brow0 + 16 + c) * NH;
    const unsigned short* wa0 = WhT + (size_t)(32 * w + c) * NH;
    const unsigned short* wa1 = WhT + (size_t)(32 * w + 16 + c) * NH;
#pragma unroll 2
    for (int ks = 0; ks < 32; ++ks) {
      const int k0 = 8 * g + 32 * ks;
      f32x4 ha = *(const f32x4*)(h0p + k0);
      f32x4 hb = *(const f32x4*)(h0p + k0 + 4);
      f32x4 hc = *(const f32x4*)(h1p + k0);
      f32x4 hd = *(const f32x4*)(h1p + k0 + 4);
      short8 bf0, bf1;
      bf0[0] = (short)f2b(ha[0]); bf0[1] = (short)f2b(ha[1]);
      bf0[2] = (short)f2b(ha[2]); bf0[3] = (short)f2b(ha[3]);
      bf0[4] = (short)f2b(hb[0]); bf0[5] = (short)f2b(hb[1]);
      bf0[6] = (short)f2b(hb[2]); bf0[7] = (short)f2b(hb[3]);
      bf1[0] = (short)f2b(hc[0]); bf1[1] = (short)f2b(hc[1]);
      bf1[2] = (short)f2b(hc[2]); bf1[3] = (short)f2b(hc[3]);
      bf1[4] = (short)f2b(hd[0]); bf1[5] = (short)f2b(hd[1]);
      bf1[6] = (short)f2b(hd[2]); bf1[7] = (short)f2b(hd[3]);
      short8 af0 = *(const short8*)(wa0 + k0);
      short8 af1 = *(const short8*)(wa1 + k0);
      pacc[0][0] = __builtin_amdgcn_mfma_f32_16x16x32_bf16(af0, bf0, pacc[0][0], 0, 0, 0);
      pacc[0][1] = __builtin_amdgcn_mfma_f32_16x16x32_bf16(af0, bf1, pacc[0][1], 0, 0, 0);
      pacc[1][0] = __builtin_amdgcn_mfma_f32_16x16x32_bf16(af1, bf0, pacc[1][0], 0, 0, 0);
      pacc[1][1] = __builtin_amdgcn_mfma_f32_16x16x32_bf16(af1, bf1, pacc[1][1], 0, 0, 0);
    }
#pragma unroll
    for (int mf = 0; mf < 2; ++mf) {
      const int d0 = 32 * w + 16 * mf + 4 * g;
      f32x4 bias = *(const f32x4*)(Wh_b + d0);
#pragma unroll
      for (int nf = 0; nf < 2; ++nf) {
        f32x4 v = pacc[mf][nf] + bias;
        unsigned int lo = (unsigned)f2b(v[0]) | ((unsigned)f2b(v[1]) << 16);
        unsigned int hi = (unsigned)f2b(v[2]) | ((unsigned)f2b(v[3]) << 16);
        uint2v pk = {lo, hi};
        *(uint2v*)(&sm.r_lds[swz(16 * nf + c, d0)]) = pk;
      }
    }
  }
  const float bs0 = bsum[32 * w + c];
  const float bs1 = bsum[32 * w + 16 + c];
  bar_sync();

  f32x4 acc2[2][2];
#pragma unroll
  for (int i = 0; i < 2; ++i)
#pragma unroll
    for (int j = 0; j < 2; ++j) acc2[i][j] = (f32x4){0.f, 0.f, 0.f, 0.f};

#pragma unroll 1
  for (int i = 0; i < NE; i += 2) {             // ping-pong, statically indexed
    const int eB = (e0 + i + 1) & 63, eC = (e0 + i + 2) & 63;
    const int pA = (e0 + i + 63) & 63, pB = (e0 + i) & 63;
    entity_body(i,     eB, pA, brow0, w, c, g, t,
                wa, wb, ba, bb, acc2, WeT, We_b, outP, sm);
    entity_body(i + 1, eC, pB, brow0, w, c, g, t,
                wb, wa, bb, ba, acc2, WeT, We_b, outP, sm);
  }
  // drain: final entity's slice (parity 1)
  store_p_slice(sm, outP, brow0, (e0 + 63) & 63, 1, t);

  // ---- epilogue: result[b][d'] via LDS transpose, coalesced nt store
  bar_sync();                 // all waves' drain LDS reads complete before obuf
#pragma unroll
  for (int mf2 = 0; mf2 < 2; ++mf2)
#pragma unroll
    for (int n = 0; n < 2; ++n) {
      float bs = n ? bs1 : bs0;
#pragma unroll
      for (int r = 0; r < 4; ++r)
        sm.obuf[(16 * mf2 + 4 * g + r) * ND + 32 * w + 16 * n + c] =
            acc2[mf2][n][r] + bs;
    }
  bar_sync();
  {
    const int orow = t >> 5, ocol = (t & 31) * 4;
#pragma unroll
    for (int it = 0; it < 4; ++it) {
      const int row = orow + 8 * it;
      f32x4 v = *(const f32x4*)(&sm.obuf[row * ND + ocol]);
      __builtin_nontemporal_store(
          v, (f32x4*)(outR + (size_t)(brow0 + row) * ND + ocol));
    }
  }
}

extern "C" void kernel_launch(void* const* d_in, const int* in_sizes, int n_in,
                              void* d_out, int out_size, void* d_ws, size_t ws_size,
                              hipStream_t stream)
{
  (void)in_sizes; (void)n_in; (void)out_size; (void)ws_size;
  const float* hidden = (const float*)d_in[0];
  const float* Wh_w   = (const float*)d_in[1];
  const float* Wh_b   = (const float*)d_in[2];
  const float* We_w   = (const float*)d_in[3];
  const float* We_b   = (const float*)d_in[4];
  float* outP = (float*)d_out;
  float* outR = outP + (size_t)NB * NE * ND;

  char* ws = (char*)d_ws;
  unsigned short* WeT = (unsigned short*)(ws);               // 2MB
  unsigned short* WhT = (unsigned short*)(ws + 2097152);     // 256KB
  float* bsum         = (float*)(ws + 2097152 + 262144);     // 512B

  k0_prep<<<1153, 256, 0, stream>>>(Wh_w, We_w, We_b, WeT, WhT, bsum);
  k2_main<<<512, 256, 0, stream>>>(hidden, WhT, Wh_b, WeT, We_b, bsum, outP, outR);
}